// Round 14
// baseline (77.360 us; speedup 1.0000x reference)
//
#include <hip/hip_runtime.h>

// Problem constants (reference: N=8192 queries, D=384, M=1024 docs)
#define N_Q   8192
#define DIM   384     // = 6 k-iters of 64 = 12 MFMA k-steps of 32
#define N_DOC 1024

typedef unsigned short ushort_t;
typedef __attribute__((ext_vector_type(8))) short bf16x8;
typedef __attribute__((ext_vector_type(4))) float f32x4;
typedef __attribute__((ext_vector_type(4))) int i32x4;

__device__ __forceinline__ float bf2f(ushort_t u) {
    union { unsigned i; float f; } c; c.i = ((unsigned)u) << 16; return c.f;
}
__device__ __forceinline__ ushort_t f2bf(float f) {   // RNE
    union { float f; unsigned u; } c; c.f = f;
    unsigned r = c.u + 0x7FFF + ((c.u >> 16) & 1);
    return (ushort_t)(r >> 16);
}
__device__ __forceinline__ void gload_lds16(const void* g, void* l) {
    __builtin_amdgcn_global_load_lds((const __attribute__((address_space(1))) void*)g,
                                     (__attribute__((address_space(3))) void*)l, 16, 0, 0);
}

// ---------------------------------------------------------------------------
// Kernel A (merged normalize + segsum):
//   8 waves per doc j; wave w scans queries [w*1024, (w+1)*1024).
//   For each matched q: load RAW f32 row, normalize in-register, accumulate
//   lab*(v*inv) in f32, write bf16 normalized row to nqb (single writer).
//   Partials combined in LDS in fixed wave order (bit-deterministic).
// ---------------------------------------------------------------------------
#define SS_WAVES 8
__global__ __launch_bounds__(512) void k_segnorm(const float* __restrict__ emb,
                                                 const float* __restrict__ label,
                                                 const int*   __restrict__ ids,
                                                 ushort_t* __restrict__ nqb,
                                                 ushort_t* __restrict__ Hb) {
    __shared__ float pacc[SS_WAVES][DIM];
    __shared__ float pden[SS_WAVES];
    int j    = blockIdx.x;
    int lane = threadIdx.x & 63;
    int w    = threadIdx.x >> 6;
    const int span = N_Q / SS_WAVES;          // 1024
    int q0 = w * span;

    float acc[6] = {0.f, 0.f, 0.f, 0.f, 0.f, 0.f};
    float den = 0.f;

    int idc = ids[q0 + lane];
    for (int base = q0; base < q0 + span; base += 64) {
        int nb = base + 64;
        int idn = (nb < q0 + span) ? ids[nb + lane] : -1;
        unsigned long long mask = __ballot(idc == j);
        while (mask) {
            int b = __builtin_ctzll(mask);
            mask &= mask - 1;
            int q = base + b;
            float lab = label[q];
            const float* row = emb + (size_t)q * DIM;
            float v[6];
            float ss = 0.f;
#pragma unroll
            for (int t = 0; t < 6; ++t) { v[t] = row[lane + 64 * t]; ss += v[t] * v[t]; }
#pragma unroll
            for (int off = 32; off; off >>= 1) ss += __shfl_xor(ss, off);
            float inv = rsqrtf(ss);
            ushort_t* o = nqb + (size_t)q * DIM;
#pragma unroll
            for (int t = 0; t < 6; ++t) {
                float nv = v[t] * inv;
                acc[t] = fmaf(lab, nv, acc[t]);
                o[lane + 64 * t] = f2bf(nv);
            }
            den += lab;
        }
        idc = idn;
    }
#pragma unroll
    for (int t = 0; t < 6; ++t) pacc[w][lane + 64 * t] = acc[t];
    if (lane == 0) pden[w] = den;
    __syncthreads();

    int d = threadIdx.x;
    if (d < DIM) {
        float s = 0.f, dn = 0.f;
#pragma unroll
        for (int ww = 0; ww < SS_WAVES; ++ww) { s += pacc[ww][d]; dn += pden[ww]; }
        float invd = (dn > 0.f) ? (1.f / dn) : 0.f;   // empty group -> 0 (never gathered)
        Hb[(size_t)j * DIM + d] = f2bf(s * invd);
    }
}

// ---------------------------------------------------------------------------
// Kernel B: T[i,j] = nq[i,:] . H[j,:]  -- bf16 MFMA 16x16x32, fp32 accum,
// bf16 output. 128x64 tile -> 1024 blocks; A+B DOUBLE-BUFFERED (48 KB LDS,
// 3 blocks/CU), 1 barrier per k-iter: stage(kq+1 -> buf^1) issued before
// MFMA(buf), __syncthreads drains both (proven race-free structure, R10).
// XOR-swizzled global_load_lds width-16.
// ---------------------------------------------------------------------------
__global__ __launch_bounds__(256) void k_gemm(const ushort_t* __restrict__ A,  // nq bf16 [N_Q][DIM]
                                              const ushort_t* __restrict__ B,  // H  bf16 [N_DOC][DIM]
                                              ushort_t* __restrict__ Tb) {     // bf16 [N_Q][N_DOC]
    __shared__ ushort_t As[2][128 * 64];   // 2 x 16 KB
    __shared__ ushort_t Bs[2][64 * 64];    // 2 x  8 KB
    int tid  = threadIdx.x;
    int lane = tid & 63, w = tid >> 6;
    int row0 = blockIdx.y * 128, col0 = blockIdx.x * 64;
    int fr = lane & 15, kg = lane >> 4;

    auto stage = [&](int kq, int bf) {
        // A-tile 128x64: 1024 granules of 16 B, 4 rounds
#pragma unroll
        for (int r = 0; r < 4; ++r) {
            int flat = r * 256 + tid;
            int row = flat >> 3, gd = flat & 7, gs = gd ^ (row & 7);
            gload_lds16(A + (size_t)(row0 + row) * DIM + kq * 64 + gs * 8,
                        &As[bf][(r * 256 + w * 64) * 8]);
        }
        // B-tile 64x64: 512 granules, 2 rounds
#pragma unroll
        for (int r = 0; r < 2; ++r) {
            int flat = r * 256 + tid;
            int row = flat >> 3, gd = flat & 7, gs = gd ^ (row & 7);
            gload_lds16(B + (size_t)(col0 + row) * DIM + kq * 64 + gs * 8,
                        &Bs[bf][(r * 256 + w * 64) * 8]);
        }
    };

    f32x4 acc[2][4];
#pragma unroll
    for (int i = 0; i < 2; ++i)
#pragma unroll
        for (int jj = 0; jj < 4; ++jj) acc[i][jj] = (f32x4)0.f;

    stage(0, 0);
    __syncthreads();                 // buf0 staged (barrier drains vmcnt)
    int cur = 0;
    for (int kq = 0; kq < 6; ++kq) {
        if (kq + 1 < 6) stage(kq + 1, cur ^ 1);    // in flight during MFMA

#pragma unroll
        for (int ks = 0; ks < 2; ++ks) {
            int kidx = ks * 4 + kg;
            bf16x8 a[2], b[4];
#pragma unroll
            for (int mi = 0; mi < 2; ++mi) {
                int m = w * 32 + mi * 16 + fr;
                a[mi] = *(const bf16x8*)&As[cur][(m * 8 + (kidx ^ (m & 7))) * 8];
            }
#pragma unroll
            for (int ni = 0; ni < 4; ++ni) {
                int n = ni * 16 + fr;
                b[ni] = *(const bf16x8*)&Bs[cur][(n * 8 + (kidx ^ (n & 7))) * 8];
            }
#pragma unroll
            for (int mi = 0; mi < 2; ++mi)
#pragma unroll
                for (int ni = 0; ni < 4; ++ni)
                    acc[mi][ni] = __builtin_amdgcn_mfma_f32_16x16x32_bf16(a[mi], b[ni], acc[mi][ni], 0, 0, 0);
        }
        __syncthreads();             // drains next buf's loads + this buf's reads
        cur ^= 1;
    }

    // C/D layout: col = lane&15, row = (lane>>4)*4 + reg   [m89]
#pragma unroll
    for (int mi = 0; mi < 2; ++mi)
#pragma unroll
        for (int ni = 0; ni < 4; ++ni)
#pragma unroll
            for (int rr = 0; rr < 4; ++rr)
                Tb[(size_t)(row0 + w * 32 + mi * 16 + kg * 4 + rr) * N_DOC
                   + col0 + ni * 16 + fr] = f2bf(acc[mi][ni][rr]);
}

// ---------------------------------------------------------------------------
// Kernel C: out[i,q] = T[i, ids[q]].  8 rows/block (1024 blocks = 4/CU).
// ids held in registers; 8 bf16 T-rows converted to f32 in 32 KB LDS;
// non-temporal f32x4 stores (write-BW bound; measured at the ~6.3 TB/s
// mixed read+write ceiling — R12 variant, best measured).
// ---------------------------------------------------------------------------
#define EROWS 8
__global__ __launch_bounds__(256) void k_expand(const ushort_t* __restrict__ Tb,
                                                const int*      __restrict__ ids,
                                                float*          __restrict__ out) {
    __shared__ float trow[EROWS * N_DOC];   // 32 KB
    int tid = threadIdx.x;
    int i0  = blockIdx.x * EROWS;

    // ids -> registers (8 x i32x4 per thread)
    i32x4 idv[N_Q / 4 / 256];
    const i32x4* id4 = (const i32x4*)ids;
#pragma unroll
    for (int it = 0; it < N_Q / 4 / 256; ++it) idv[it] = id4[it * 256 + tid];

    // stage 8 bf16 rows -> f32 LDS (1024 chunks of 16 B)
    const bf16x8* Tv = (const bf16x8*)(Tb + (size_t)i0 * N_DOC);
#pragma unroll
    for (int c = 0; c < 4; ++c) {
        int chunk = c * 256 + tid;
        bf16x8 v = Tv[chunk];
        f32x4 lo = { bf2f((ushort_t)v[0]), bf2f((ushort_t)v[1]), bf2f((ushort_t)v[2]), bf2f((ushort_t)v[3]) };
        f32x4 hi = { bf2f((ushort_t)v[4]), bf2f((ushort_t)v[5]), bf2f((ushort_t)v[6]), bf2f((ushort_t)v[7]) };
        *(f32x4*)&trow[chunk * 8]     = lo;
        *(f32x4*)&trow[chunk * 8 + 4] = hi;
    }
    __syncthreads();

#pragma unroll
    for (int it = 0; it < N_Q / 4 / 256; ++it) {   // 8 iterations over q
        int q4 = it * 256 + tid;
        i32x4 id = idv[it];
#pragma unroll
        for (int r = 0; r < EROWS; ++r) {
            const float* tr = &trow[r * N_DOC];
            f32x4 v = { tr[id.x], tr[id.y], tr[id.z], tr[id.w] };
            __builtin_nontemporal_store(v, (f32x4*)(out + (size_t)(i0 + r) * N_Q) + q4);
        }
    }
}

// ---------------------------------------------------------------------------
extern "C" void kernel_launch(void* const* d_in, const int* in_sizes, int n_in,
                              void* d_out, int out_size, void* d_ws, size_t ws_size,
                              hipStream_t stream) {
    const float* emb   = (const float*)d_in[0];
    const float* label = (const float*)d_in[1];
    const int*   ids   = (const int*)d_in[2];
    float* out = (float*)d_out;

    // workspace: nqb bf16 [N_Q*DIM] | Hb bf16 [N_DOC*DIM] | Tb bf16 [N_Q*N_DOC]
    ushort_t* nqb = (ushort_t*)d_ws;
    ushort_t* Hb  = nqb + (size_t)N_Q * DIM;
    ushort_t* Tb  = Hb + (size_t)N_DOC * DIM;

    k_segnorm<<<N_DOC, 512, 0, stream>>>(emb, label, ids, nqb, Hb);
    k_gemm<<<dim3(N_DOC / 64, N_Q / 128), 256, 0, stream>>>(nqb, Hb, Tb);
    k_expand<<<N_Q / EROWS, 256, 0, stream>>>(Tb, ids, out);
}

// Round 15
// 74.742 us; speedup vs baseline: 1.0350x; 1.0350x over previous
//
#include <hip/hip_runtime.h>

// Problem constants (reference: N=8192 queries, D=384, M=1024 docs)
#define N_Q   8192
#define DIM   384     // = 6 k-iters of 64 = 12 MFMA k-steps of 32
#define N_DOC 1024

typedef unsigned short ushort_t;
typedef __attribute__((ext_vector_type(8))) short bf16x8;
typedef __attribute__((ext_vector_type(4))) float f32x4;
typedef __attribute__((ext_vector_type(4))) int i32x4;

__device__ __forceinline__ float bf2f(ushort_t u) {
    union { unsigned i; float f; } c; c.i = ((unsigned)u) << 16; return c.f;
}
__device__ __forceinline__ ushort_t f2bf(float f) {   // RNE
    union { float f; unsigned u; } c; c.f = f;
    unsigned r = c.u + 0x7FFF + ((c.u >> 16) & 1);
    return (ushort_t)(r >> 16);
}
__device__ __forceinline__ void gload_lds16(const void* g, void* l) {
    __builtin_amdgcn_global_load_lds((const __attribute__((address_space(1))) void*)g,
                                     (__attribute__((address_space(3))) void*)l, 16, 0, 0);
}

// ---------------------------------------------------------------------------
// Kernel A (merged normalize + segsum):
//   8 waves per doc j; wave w scans queries [w*1024, (w+1)*1024).
//   For each matched q: load RAW f32 row, normalize in-register, accumulate
//   lab*(v*inv) in f32, write bf16 normalized row to nqb (single writer).
//   Partials combined in LDS in fixed wave order (bit-deterministic).
// ---------------------------------------------------------------------------
#define SS_WAVES 8
__global__ __launch_bounds__(512) void k_segnorm(const float* __restrict__ emb,
                                                 const float* __restrict__ label,
                                                 const int*   __restrict__ ids,
                                                 ushort_t* __restrict__ nqb,
                                                 ushort_t* __restrict__ Hb) {
    __shared__ float pacc[SS_WAVES][DIM];
    __shared__ float pden[SS_WAVES];
    int j    = blockIdx.x;
    int lane = threadIdx.x & 63;
    int w    = threadIdx.x >> 6;
    const int span = N_Q / SS_WAVES;          // 1024
    int q0 = w * span;

    float acc[6] = {0.f, 0.f, 0.f, 0.f, 0.f, 0.f};
    float den = 0.f;

    int idc = ids[q0 + lane];
    for (int base = q0; base < q0 + span; base += 64) {
        int nb = base + 64;
        int idn = (nb < q0 + span) ? ids[nb + lane] : -1;
        unsigned long long mask = __ballot(idc == j);
        while (mask) {
            int b = __builtin_ctzll(mask);
            mask &= mask - 1;
            int q = base + b;
            float lab = label[q];
            const float* row = emb + (size_t)q * DIM;
            float v[6];
            float ss = 0.f;
#pragma unroll
            for (int t = 0; t < 6; ++t) { v[t] = row[lane + 64 * t]; ss += v[t] * v[t]; }
#pragma unroll
            for (int off = 32; off; off >>= 1) ss += __shfl_xor(ss, off);
            float inv = rsqrtf(ss);
            ushort_t* o = nqb + (size_t)q * DIM;
#pragma unroll
            for (int t = 0; t < 6; ++t) {
                float nv = v[t] * inv;
                acc[t] = fmaf(lab, nv, acc[t]);
                o[lane + 64 * t] = f2bf(nv);
            }
            den += lab;
        }
        idc = idn;
    }
#pragma unroll
    for (int t = 0; t < 6; ++t) pacc[w][lane + 64 * t] = acc[t];
    if (lane == 0) pden[w] = den;
    __syncthreads();

    int d = threadIdx.x;
    if (d < DIM) {
        float s = 0.f, dn = 0.f;
#pragma unroll
        for (int ww = 0; ww < SS_WAVES; ++ww) { s += pacc[ww][d]; dn += pden[ww]; }
        float invd = (dn > 0.f) ? (1.f / dn) : 0.f;   // empty group -> 0 (never gathered)
        Hb[(size_t)j * DIM + d] = f2bf(s * invd);
    }
}

// ---------------------------------------------------------------------------
// Kernel B: T[i,j] = nq[i,:] . H[j,:]  -- bf16 MFMA 16x16x32, fp32 accum,
// bf16 output. 128x64 tile -> 1024 blocks (4/CU, full machine). 4 waves;
// wave w owns rows [w*32, w*32+32) x all 64 cols (2 m-frags x 4 n-frags).
// Single-buffered 2-barrier staging (proven race-free); XOR-swizzled
// global_load_lds width-16; TLP from 4 blocks/CU hides staging latency.
// ---------------------------------------------------------------------------
__global__ __launch_bounds__(256) void k_gemm(const ushort_t* __restrict__ A,  // nq bf16 [N_Q][DIM]
                                              const ushort_t* __restrict__ B,  // H  bf16 [N_DOC][DIM]
                                              ushort_t* __restrict__ Tb) {     // bf16 [N_Q][N_DOC]
    __shared__ ushort_t As[128 * 64];   // 16 KB: elem offset = (row*8 + slot)*8
    __shared__ ushort_t Bs[64 * 64];    //  8 KB
    int tid  = threadIdx.x;
    int lane = tid & 63, w = tid >> 6;
    int row0 = blockIdx.y * 128, col0 = blockIdx.x * 64;
    int fr = lane & 15, kg = lane >> 4;

    f32x4 acc[2][4];
#pragma unroll
    for (int i = 0; i < 2; ++i)
#pragma unroll
        for (int jj = 0; jj < 4; ++jj) acc[i][jj] = (f32x4)0.f;

    for (int kq = 0; kq < 6; ++kq) {
        // stage A-tile 128x64: 1024 granules of 16 B, 4 rounds
#pragma unroll
        for (int r = 0; r < 4; ++r) {
            int flat = r * 256 + tid;
            int row = flat >> 3, gd = flat & 7, gs = gd ^ (row & 7);
            gload_lds16(A + (size_t)(row0 + row) * DIM + kq * 64 + gs * 8,
                        &As[(r * 256 + w * 64) * 8]);
        }
        // stage B-tile 64x64: 512 granules, 2 rounds
#pragma unroll
        for (int r = 0; r < 2; ++r) {
            int flat = r * 256 + tid;
            int row = flat >> 3, gd = flat & 7, gs = gd ^ (row & 7);
            gload_lds16(B + (size_t)(col0 + row) * DIM + kq * 64 + gs * 8,
                        &Bs[(r * 256 + w * 64) * 8]);
        }
        __syncthreads();   // drains vmcnt -> staged data visible

#pragma unroll
        for (int ks = 0; ks < 2; ++ks) {
            int kidx = ks * 4 + kg;
            bf16x8 a[2], b[4];
#pragma unroll
            for (int mi = 0; mi < 2; ++mi) {
                int m = w * 32 + mi * 16 + fr;
                a[mi] = *(const bf16x8*)&As[(m * 8 + (kidx ^ (m & 7))) * 8];
            }
#pragma unroll
            for (int ni = 0; ni < 4; ++ni) {
                int n = ni * 16 + fr;
                b[ni] = *(const bf16x8*)&Bs[(n * 8 + (kidx ^ (n & 7))) * 8];
            }
#pragma unroll
            for (int mi = 0; mi < 2; ++mi)
#pragma unroll
                for (int ni = 0; ni < 4; ++ni)
                    acc[mi][ni] = __builtin_amdgcn_mfma_f32_16x16x32_bf16(a[mi], b[ni], acc[mi][ni], 0, 0, 0);
        }
        __syncthreads();   // protect As/Bs before restage
    }

    // C/D layout: col = lane&15, row = (lane>>4)*4 + reg   [m89]
#pragma unroll
    for (int mi = 0; mi < 2; ++mi)
#pragma unroll
        for (int ni = 0; ni < 4; ++ni)
#pragma unroll
            for (int rr = 0; rr < 4; ++rr)
                Tb[(size_t)(row0 + w * 32 + mi * 16 + kg * 4 + rr) * N_DOC
                   + col0 + ni * 16 + fr] = f2bf(acc[mi][ni][rr]);
}

// ---------------------------------------------------------------------------
// Kernel C: out[i,q] = T[i, ids[q]].  8 rows/block (1024 blocks = 4/CU).
// ids held in registers; 8 bf16 T-rows converted to f32 in 32 KB LDS;
// non-temporal f32x4 stores (write-BW bound; at the ~6.3 TB/s mixed
// read+write ceiling — best-measured variant, R12).
// ---------------------------------------------------------------------------
#define EROWS 8
__global__ __launch_bounds__(256) void k_expand(const ushort_t* __restrict__ Tb,
                                                const int*      __restrict__ ids,
                                                float*          __restrict__ out) {
    __shared__ float trow[EROWS * N_DOC];   // 32 KB
    int tid = threadIdx.x;
    int i0  = blockIdx.x * EROWS;

    // ids -> registers (8 x i32x4 per thread)
    i32x4 idv[N_Q / 4 / 256];
    const i32x4* id4 = (const i32x4*)ids;
#pragma unroll
    for (int it = 0; it < N_Q / 4 / 256; ++it) idv[it] = id4[it * 256 + tid];

    // stage 8 bf16 rows -> f32 LDS (1024 chunks of 16 B)
    const bf16x8* Tv = (const bf16x8*)(Tb + (size_t)i0 * N_DOC);
#pragma unroll
    for (int c = 0; c < 4; ++c) {
        int chunk = c * 256 + tid;
        bf16x8 v = Tv[chunk];
        f32x4 lo = { bf2f((ushort_t)v[0]), bf2f((ushort_t)v[1]), bf2f((ushort_t)v[2]), bf2f((ushort_t)v[3]) };
        f32x4 hi = { bf2f((ushort_t)v[4]), bf2f((ushort_t)v[5]), bf2f((ushort_t)v[6]), bf2f((ushort_t)v[7]) };
        *(f32x4*)&trow[chunk * 8]     = lo;
        *(f32x4*)&trow[chunk * 8 + 4] = hi;
    }
    __syncthreads();

#pragma unroll
    for (int it = 0; it < N_Q / 4 / 256; ++it) {   // 8 iterations over q
        int q4 = it * 256 + tid;
        i32x4 id = idv[it];
#pragma unroll
        for (int r = 0; r < EROWS; ++r) {
            const float* tr = &trow[r * N_DOC];
            f32x4 v = { tr[id.x], tr[id.y], tr[id.z], tr[id.w] };
            __builtin_nontemporal_store(v, (f32x4*)(out + (size_t)(i0 + r) * N_Q) + q4);
        }
    }
}

// ---------------------------------------------------------------------------
extern "C" void kernel_launch(void* const* d_in, const int* in_sizes, int n_in,
                              void* d_out, int out_size, void* d_ws, size_t ws_size,
                              hipStream_t stream) {
    const float* emb   = (const float*)d_in[0];
    const float* label = (const float*)d_in[1];
    const int*   ids   = (const int*)d_in[2];
    float* out = (float*)d_out;

    // workspace: nqb bf16 [N_Q*DIM] | Hb bf16 [N_DOC*DIM] | Tb bf16 [N_Q*N_DOC]
    ushort_t* nqb = (ushort_t*)d_ws;
    ushort_t* Hb  = nqb + (size_t)N_Q * DIM;
    ushort_t* Tb  = Hb + (size_t)N_DOC * DIM;

    k_segnorm<<<N_DOC, 512, 0, stream>>>(emb, label, ids, nqb, Hb);
    k_gemm<<<dim3(N_DOC / 64, N_Q / 128), 256, 0, stream>>>(nqb, Hb, Tb);
    k_expand<<<N_Q / EROWS, 256, 0, stream>>>(Tb, ids, out);
}